// Round 1
// baseline (406.271 us; speedup 1.0000x reference)
//
#include <hip/hip_runtime.h>

#define N_D 256      // embedding dim
#define N_K 512      // centroids
#define BN  64       // rows per block
#define DT  16       // d-chunk staged in LDS
#define LMBDA 0.25f

// ---------------- kernel 0: c_sq[k] = sum_d C[k][d]^2 ----------------
__global__ __launch_bounds__(64) void csq_kernel(const float* __restrict__ C,
                                                 float* __restrict__ csq) {
    const int k = blockIdx.x;
    const int lane = threadIdx.x;
    float4 v = *(const float4*)(C + (size_t)k * N_D + lane * 4);
    float s = v.x * v.x + v.y * v.y + v.z * v.z + v.w * v.w;
#pragma unroll
    for (int m = 1; m <= 32; m <<= 1) s += __shfl_xor(s, m, 64);
    if (lane == 0) csq[k] = s;
}

// ---------------- kernel 1: fused GEMM + max/argmax ----------------
// block: 256 threads = 8 waves-worth of (tx 0..31, ty 0..7)
// each block: rows n0..n0+63, ALL 512 cols.
// thread tile: 8 rows (8*ty..8*ty+7) x 16 cols (4*tx + 128*m + q).
__global__ __launch_bounds__(256, 2) void kmeans_main(
    const float* __restrict__ E, const float* __restrict__ C,
    const float* __restrict__ csq, float* __restrict__ out,
    float* __restrict__ partials) {
    __shared__ float At[DT][BN];    // d-major (transposed) A tile: 4 KB
    __shared__ float Bt[DT][N_K];   // d-major (transposed) B tile: 32 KB
    __shared__ float wsum[4];

    const int tid = threadIdx.x;
    const int tx = tid & 31;
    const int ty = tid >> 5;
    const int n0 = blockIdx.x * BN;

    float acc[8][16];
#pragma unroll
    for (int i = 0; i < 8; ++i)
#pragma unroll
        for (int j = 0; j < 16; ++j) acc[i][j] = 0.f;

    float e2part = 0.f;  // sum of squares of A elements this thread stages
    const int an = tid >> 2, ajb = tid & 3;

    for (int t = 0; t < N_D / DT; ++t) {
        const int d0 = t * DT;
        // ---- stage A chunk (64 rows x 16 d), transposed into At ----
        {
            float4 v = *(const float4*)(E + (size_t)(n0 + an) * N_D + d0 + ajb * 4);
            e2part += v.x * v.x + v.y * v.y + v.z * v.z + v.w * v.w;
            At[ajb * 4 + 0][an] = v.x;
            At[ajb * 4 + 1][an] = v.y;
            At[ajb * 4 + 2][an] = v.z;
            At[ajb * 4 + 3][an] = v.w;
        }
        // ---- stage B chunk (512 rows x 16 d), transposed into Bt ----
#pragma unroll
        for (int it = 0; it < 8; ++it) {
            int i = tid + it * 256;
            int k = i >> 2, jb = i & 3;
            float4 v = *(const float4*)(C + (size_t)k * N_D + d0 + jb * 4);
            Bt[jb * 4 + 0][k] = v.x;
            Bt[jb * 4 + 1][k] = v.y;
            Bt[jb * 4 + 2][k] = v.z;
            Bt[jb * 4 + 3][k] = v.w;
        }
        __syncthreads();
        // ---- compute: 16 d-steps, 128 FMA each ----
#pragma unroll 4
        for (int d = 0; d < DT; ++d) {
            float a[8], b[16];
            *(float4*)&a[0] = *(const float4*)&At[d][ty * 8];
            *(float4*)&a[4] = *(const float4*)&At[d][ty * 8 + 4];
#pragma unroll
            for (int m = 0; m < 4; ++m)
                *(float4*)&b[m * 4] = *(const float4*)&Bt[d][tx * 4 + m * 128];
#pragma unroll
            for (int i = 0; i < 8; ++i)
#pragma unroll
                for (int j = 0; j < 16; ++j) acc[i][j] += a[i] * b[j];
        }
        __syncthreads();
    }

    // ---- epilogue: s[n][k] = c_sq[k] - 2*cross; per-row max+argmax ----
    float cs[16];
#pragma unroll
    for (int m = 0; m < 4; ++m)
        *(float4*)&cs[m * 4] = *(const float4*)(csq + tx * 4 + m * 128);

    float m_sum = 0.f;
#pragma unroll
    for (int i = 0; i < 8; ++i) {
        float bv = -3.4e38f;
        int bi = 0;
#pragma unroll
        for (int m = 0; m < 4; ++m)
#pragma unroll
            for (int q = 0; q < 4; ++q) {
                float val = cs[m * 4 + q] - 2.f * acc[i][m * 4 + q];
                int col = tx * 4 + m * 128 + q;  // increasing over (m,q)
                if (val > bv) { bv = val; bi = col; }
            }
        // reduce across the 32 tx-lanes (each half-wave owns one row set);
        // tie-break: smaller index wins (jnp.argmax first-occurrence).
#pragma unroll
        for (int mk = 1; mk <= 16; mk <<= 1) {
            float ov = __shfl_xor(bv, mk, 64);
            int oi = __shfl_xor(bi, mk, 64);
            if (ov > bv || (ov == bv && oi < bi)) { bv = ov; bi = oi; }
        }
        if (tx == 0) {
            out[1 + n0 + ty * 8 + i] = (float)bi;  // assignment as float
            m_sum += bv;                           // max_k (c_sq - 2 cross)
        }
    }

    // ---- block partial: sum(e^2 staged) + sum(row maxima) ----
    float tot = e2part + m_sum;
#pragma unroll
    for (int mk = 1; mk <= 32; mk <<= 1) tot += __shfl_xor(tot, mk, 64);
    const int lane = tid & 63, wid = tid >> 6;
    if (lane == 0) wsum[wid] = tot;
    __syncthreads();
    if (tid == 0) partials[blockIdx.x] = wsum[0] + wsum[1] + wsum[2] + wsum[3];
}

// ---------------- kernel 2: deterministic final reduction ----------------
__global__ __launch_bounds__(256) void finalize(const float* __restrict__ partials,
                                                int np, float* __restrict__ out) {
    float s = 0.f;
    for (int i = threadIdx.x; i < np; i += 256) s += partials[i];
#pragma unroll
    for (int mk = 1; mk <= 32; mk <<= 1) s += __shfl_xor(s, mk, 64);
    __shared__ float w[4];
    const int lane = threadIdx.x & 63, wid = threadIdx.x >> 6;
    if (lane == 0) w[wid] = s;
    __syncthreads();
    if (threadIdx.x == 0) out[0] = (LMBDA * LMBDA) * (w[0] + w[1] + w[2] + w[3]);
}

extern "C" void kernel_launch(void* const* d_in, const int* in_sizes, int n_in,
                              void* d_out, int out_size, void* d_ws, size_t ws_size,
                              hipStream_t stream) {
    (void)n_in; (void)out_size; (void)ws_size;
    const float* E = (const float*)d_in[0];
    const float* C = (const float*)d_in[1];
    float* out = (float*)d_out;
    float* wsf = (float*)d_ws;
    float* csq = wsf;            // 512 floats
    float* partials = wsf + 512; // N/BN floats

    const int N = in_sizes[0] / N_D;      // 131072
    const int nblk = N / BN;              // 2048

    csq_kernel<<<N_K, 64, 0, stream>>>(C, csq);
    kmeans_main<<<nblk, 256, 0, stream>>>(E, C, csq, out, partials);
    finalize<<<1, 256, 0, stream>>>(partials, nblk, out);
}

// Round 2
// 202.477 us; speedup vs baseline: 2.0065x; 2.0065x over previous
//
#include <hip/hip_runtime.h>

#define ND 256       // embedding dim
#define NK 512       // centroids
#define LM2 0.0625f  // lambda^2
#define DELTA 0.05f  // rescore trigger: approx top-2 gap below this -> exact fp32 rescore

typedef __bf16 bf16x8 __attribute__((ext_vector_type(8)));
typedef float f32x4 __attribute__((ext_vector_type(4)));
typedef unsigned short u16x8 __attribute__((ext_vector_type(8)));
typedef unsigned short u16x4 __attribute__((ext_vector_type(4)));

// LDS tiles are [row][32 k] bf16 (row stride 32 elems = 64B). XOR swizzle on the
// element index (flips bits 3..5) makes the MFMA b128 frag reads conflict-free
// (2-way max = free) while staying bijective within each 8-row/512B group.
#define SWZ(r, c) ((((r) << 5) + (c)) ^ (((r)&7) << 3))

// ---------------- prep: csq[k] and bf16 hi/lo split of centroids ----------------
__global__ __launch_bounds__(64) void prep_kernel(const float* __restrict__ Cg,
                                                  float* __restrict__ csq,
                                                  unsigned short* __restrict__ Chi,
                                                  unsigned short* __restrict__ Clo) {
    const int k = blockIdx.x, lane = threadIdx.x;
    float4 v = *(const float4*)(Cg + (size_t)k * ND + lane * 4);
    float s = v.x * v.x + v.y * v.y + v.z * v.z + v.w * v.w;
#pragma unroll
    for (int m = 1; m <= 32; m <<= 1) s += __shfl_xor(s, m, 64);
    if (lane == 0) csq[k] = s;
    float vv[4] = {v.x, v.y, v.z, v.w};
    u16x4 h, l;
#pragma unroll
    for (int j = 0; j < 4; ++j) {
        unsigned b = __builtin_bit_cast(unsigned, vv[j]);
        h[j] = (unsigned short)(b >> 16);
        float hif = __builtin_bit_cast(float, b & 0xffff0000u);
        float lo = vv[j] - hif;  // exact in fp32
        l[j] = (unsigned short)(__builtin_bit_cast(unsigned, lo) >> 16);
    }
    *(u16x4*)(Chi + (size_t)k * ND + lane * 4) = h;
    *(u16x4*)(Clo + (size_t)k * ND + lane * 4) = l;
}

// ---------------- main: split-bf16 MFMA GEMM + per-row top-2 ----------------
// grid: 1024 row-tiles x 4 col-blocks (consecutive bids share E rows -> L2/L3 reuse)
// block: 256 threads = 4 waves (wr,wc in 2x2), wave tile 64x64, 4x4 frags of 16x16x32.
__global__ __launch_bounds__(256, 2) void kmeans_mfma(
    const float* __restrict__ E, const unsigned short* __restrict__ Chi,
    const unsigned short* __restrict__ Clo, const float* __restrict__ csq,
    float* __restrict__ partials, float* __restrict__ e2s) {
    __shared__ unsigned short Ah[4096], Al[4096], Bh[4096], Bl[4096];  // 4 x 8KB
    __shared__ float mbuf[128][2][4];
    __shared__ float wsum[4];

    const int tid = threadIdx.x;
    const int rowtile = blockIdx.x >> 2, colblk = blockIdx.x & 3;
    const int rowbase = rowtile << 7;
    const int colbase = colblk << 7;

    const int lane = tid & 63, wid = tid >> 6;
    const int wr = wid >> 1, wc = wid & 1;
    const int l15 = lane & 15, l4 = lane >> 4;

    f32x4 acc[4][4] = {};
    float e2 = 0.f;

    const float* Ebase = E + (size_t)rowbase * ND;
    const unsigned short* ChiB = Chi + (size_t)colbase * ND;
    const unsigned short* CloB = Clo + (size_t)colbase * ND;

    int arow[4], adq[4];
#pragma unroll
    for (int r = 0; r < 4; ++r) { int q = tid + r * 256; arow[r] = q >> 3; adq[r] = (q & 7) * 4; }
    int brow[2], bdo[2];
#pragma unroll
    for (int r = 0; r < 2; ++r) { int o = tid + r * 256; brow[r] = o >> 2; bdo[r] = (o & 3) * 8; }

    // prologue: global loads for t=0
    float4 areg[4];
    u16x8 bhreg[2], blreg[2];
#pragma unroll
    for (int r = 0; r < 4; ++r) areg[r] = *(const float4*)(Ebase + (size_t)arow[r] * ND + adq[r]);
#pragma unroll
    for (int r = 0; r < 2; ++r) {
        bhreg[r] = *(const u16x8*)(ChiB + (size_t)brow[r] * ND + bdo[r]);
        blreg[r] = *(const u16x8*)(CloB + (size_t)brow[r] * ND + bdo[r]);
    }

    for (int t = 0; t < 8; ++t) {
        // ---- convert + LDS write current chunk ----
#pragma unroll
        for (int r = 0; r < 4; ++r) {
            float4 v = areg[r];
            if (colblk == 0) e2 += v.x * v.x + v.y * v.y + v.z * v.z + v.w * v.w;
            float vv[4] = {v.x, v.y, v.z, v.w};
            u16x4 h, l;
#pragma unroll
            for (int j = 0; j < 4; ++j) {
                unsigned b = __builtin_bit_cast(unsigned, vv[j]);
                h[j] = (unsigned short)(b >> 16);
                float hif = __builtin_bit_cast(float, b & 0xffff0000u);
                float lo = vv[j] - hif;
                l[j] = (unsigned short)(__builtin_bit_cast(unsigned, lo) >> 16);
            }
            const int off = SWZ(arow[r], adq[r]);
            *(u16x4*)&Ah[off] = h;
            *(u16x4*)&Al[off] = l;
        }
#pragma unroll
        for (int r = 0; r < 2; ++r) {
            const int off = SWZ(brow[r], bdo[r]);
            *(u16x8*)&Bh[off] = bhreg[r];
            *(u16x8*)&Bl[off] = blreg[r];
        }
        // ---- prefetch next chunk (in flight across the MFMA phase) ----
        if (t < 7) {
            const int d0 = (t + 1) * 32;
#pragma unroll
            for (int r = 0; r < 4; ++r)
                areg[r] = *(const float4*)(Ebase + (size_t)arow[r] * ND + d0 + adq[r]);
#pragma unroll
            for (int r = 0; r < 2; ++r) {
                bhreg[r] = *(const u16x8*)(ChiB + (size_t)brow[r] * ND + d0 + bdo[r]);
                blreg[r] = *(const u16x8*)(CloB + (size_t)brow[r] * ND + d0 + bdo[r]);
            }
        }
        __syncthreads();
        // ---- fragments + 48 MFMA (hh + hl + lh into one fp32 acc) ----
        bf16x8 fah[4], fal[4], fbh[4], fbl[4];
#pragma unroll
        for (int m = 0; m < 4; ++m) {
            const int off = SWZ(wr * 64 + m * 16 + l15, l4 * 8);
            fah[m] = __builtin_bit_cast(bf16x8, *(const u16x8*)&Ah[off]);
            fal[m] = __builtin_bit_cast(bf16x8, *(const u16x8*)&Al[off]);
        }
#pragma unroll
        for (int n = 0; n < 4; ++n) {
            const int off = SWZ(wc * 64 + n * 16 + l15, l4 * 8);
            fbh[n] = __builtin_bit_cast(bf16x8, *(const u16x8*)&Bh[off]);
            fbl[n] = __builtin_bit_cast(bf16x8, *(const u16x8*)&Bl[off]);
        }
#pragma unroll
        for (int m = 0; m < 4; ++m)
#pragma unroll
            for (int n = 0; n < 4; ++n) {
                acc[m][n] = __builtin_amdgcn_mfma_f32_16x16x32_bf16(fah[m], fbh[n], acc[m][n], 0, 0, 0);
                acc[m][n] = __builtin_amdgcn_mfma_f32_16x16x32_bf16(fah[m], fbl[n], acc[m][n], 0, 0, 0);
                acc[m][n] = __builtin_amdgcn_mfma_f32_16x16x32_bf16(fal[m], fbh[n], acc[m][n], 0, 0, 0);
            }
        __syncthreads();
    }

    // ---- epilogue: per-row top-2 of s = csq[k] - 2*cross over this block's 128 cols ----
#pragma unroll
    for (int m = 0; m < 4; ++m) {
#pragma unroll
        for (int j = 0; j < 4; ++j) {
            float v1 = -3.4e38f, v2 = -3.4e38f;
            int i1 = 0, i2 = 0;
#pragma unroll
            for (int n = 0; n < 4; ++n) {
                const int col = colbase + wc * 64 + n * 16 + l15;
                const float s = csq[col] - 2.0f * acc[m][n][j];
                if (s > v1) { v2 = v1; i2 = i1; v1 = s; i1 = col; }
                else if (s > v2) { v2 = s; i2 = col; }
            }
            // merge across the 16 lanes (l15) of this row group; min-index on ties
#pragma unroll
            for (int mk = 1; mk <= 8; mk <<= 1) {
                float ov1 = __shfl_xor(v1, mk, 64); int oi1 = __shfl_xor(i1, mk, 64);
                float ov2 = __shfl_xor(v2, mk, 64); int oi2 = __shfl_xor(i2, mk, 64);
                bool af = (v1 > ov1) || (v1 == ov1 && i1 < oi1);
                float f1 = af ? v1 : ov1; int g1 = af ? i1 : oi1;
                float c1 = af ? v2 : ov2; int d1 = af ? i2 : oi2;
                float c2 = af ? ov1 : v1; int d2 = af ? oi1 : i1;
                bool cf = (c1 > c2) || (c1 == c2 && d1 < d2);
                v1 = f1; i1 = g1; v2 = cf ? c1 : c2; i2 = cf ? d1 : d2;
            }
            if (l15 == 0) {
                const int rl = wr * 64 + m * 16 + l4 * 4 + j;
                mbuf[rl][wc][0] = v1; mbuf[rl][wc][1] = (float)i1;
                mbuf[rl][wc][2] = v2; mbuf[rl][wc][3] = (float)i2;
            }
        }
    }
    float tot = e2;
    if (colblk == 0) {
#pragma unroll
        for (int mk = 1; mk <= 32; mk <<= 1) tot += __shfl_xor(tot, mk, 64);
        if (lane == 0) wsum[wid] = tot;
    }
    __syncthreads();
    if (tid < 128) {
        float a1 = mbuf[tid][0][0]; int ai1 = (int)mbuf[tid][0][1];
        float a2 = mbuf[tid][0][2]; int ai2 = (int)mbuf[tid][0][3];
        float b1 = mbuf[tid][1][0]; int bi1 = (int)mbuf[tid][1][1];
        float b2 = mbuf[tid][1][2]; int bi2 = (int)mbuf[tid][1][3];
        bool af = (a1 > b1) || (a1 == b1 && ai1 < bi1);
        float f1 = af ? a1 : b1; int g1 = af ? ai1 : bi1;
        float c1 = af ? a2 : b2; int d1 = af ? ai2 : bi2;
        float c2 = af ? b1 : a1; int d2 = af ? bi1 : ai1;
        bool cf = (c1 > c2) || (c1 == c2 && d1 < d2);
        float f2 = cf ? c1 : c2; int g2 = cf ? d1 : d2;
        float4 o = {f1, (float)g1, f2, (float)g2};
        *(float4*)(partials + ((size_t)(rowbase + tid) * 4 + colblk) * 4) = o;
    }
    if (colblk == 0 && tid == 0) e2s[rowtile] = wsum[0] + wsum[1] + wsum[2] + wsum[3];
}

// ---------------- combine: merge 4 col-block top-2s, rescore near-ties ----------------
__global__ __launch_bounds__(256) void combine_kernel(
    const float* __restrict__ partials, const float* __restrict__ csq,
    const float* __restrict__ E, const float* __restrict__ Cg,
    float* __restrict__ out, float* __restrict__ sum2) {
    const int n = blockIdx.x * 256 + threadIdx.x;
    const float4* p = (const float4*)(partials + (size_t)n * 16);
    float4 a = p[0];
    float v1 = a.x; int i1 = (int)a.y; float v2 = a.z; int i2 = (int)a.w;
#pragma unroll
    for (int cb = 1; cb < 4; ++cb) {
        float4 b = p[cb];
        float b1 = b.x; int j1 = (int)b.y; float b2 = b.z; int j2 = (int)b.w;
        bool af = (v1 > b1) || (v1 == b1 && i1 < j1);
        float f1 = af ? v1 : b1; int g1 = af ? i1 : j1;
        float c1 = af ? v2 : b2; int d1 = af ? i2 : j2;
        float c2 = af ? b1 : v1; int d2 = af ? j1 : i1;
        bool cf = (c1 > c2) || (c1 == c2 && d1 < d2);
        v1 = f1; i1 = g1; v2 = cf ? c1 : c2; i2 = cf ? d1 : d2;
    }
    if (v1 - v2 <= DELTA) {  // near-tie: exact fp32 rescore of both candidates
        const float* e = E + (size_t)n * ND;
        const float* c1p = Cg + (size_t)i1 * ND;
        const float* c2p = Cg + (size_t)i2 * ND;
        float d1 = 0.f, d2 = 0.f;
        for (int d = 0; d < ND; d += 4) {
            float4 ev = *(const float4*)(e + d);
            float4 cv1 = *(const float4*)(c1p + d);
            float4 cv2 = *(const float4*)(c2p + d);
            d1 += ev.x * cv1.x + ev.y * cv1.y + ev.z * cv1.z + ev.w * cv1.w;
            d2 += ev.x * cv2.x + ev.y * cv2.y + ev.z * cv2.z + ev.w * cv2.w;
        }
        float s1 = csq[i1] - 2.f * d1;
        float s2 = csq[i2] - 2.f * d2;
        if (s2 > s1 || (s2 == s1 && i2 < i1)) { v1 = s2; i1 = i2; } else { v1 = s1; }
    }
    out[1 + n] = (float)i1;
    float s = v1;
#pragma unroll
    for (int mk = 1; mk <= 32; mk <<= 1) s += __shfl_xor(s, mk, 64);
    __shared__ float w[4];
    const int lane = threadIdx.x & 63, wd = threadIdx.x >> 6;
    if (lane == 0) w[wd] = s;
    __syncthreads();
    if (threadIdx.x == 0) sum2[blockIdx.x] = w[0] + w[1] + w[2] + w[3];
}

// ---------------- final: loss = lambda^2 * (sum e^2 + sum row maxima) ----------------
__global__ __launch_bounds__(256) void final_kernel(const float* __restrict__ e2s,
                                                    const float* __restrict__ sum2,
                                                    float* __restrict__ out) {
    float s = 0.f;
    for (int i = threadIdx.x; i < 1024; i += 256) s += e2s[i];
    for (int i = threadIdx.x; i < 512; i += 256) s += sum2[i];
#pragma unroll
    for (int mk = 1; mk <= 32; mk <<= 1) s += __shfl_xor(s, mk, 64);
    __shared__ float w[4];
    const int lane = threadIdx.x & 63, wd = threadIdx.x >> 6;
    if (lane == 0) w[wd] = s;
    __syncthreads();
    if (threadIdx.x == 0) out[0] = LM2 * (w[0] + w[1] + w[2] + w[3]);
}

extern "C" void kernel_launch(void* const* d_in, const int* in_sizes, int n_in,
                              void* d_out, int out_size, void* d_ws, size_t ws_size,
                              hipStream_t stream) {
    (void)n_in; (void)out_size; (void)ws_size;
    const float* E = (const float*)d_in[0];
    const float* Cg = (const float*)d_in[1];
    float* out = (float*)d_out;

    // ws layout (floats): csq[512] | e2s[1024] | sum2[512] | Chi (256KB) | Clo (256KB) | partials (8MB)
    float* wsf = (float*)d_ws;
    float* csq = wsf;
    float* e2s = wsf + 512;
    float* sum2 = wsf + 1536;
    unsigned short* Chi = (unsigned short*)(wsf + 2048);
    unsigned short* Clo = (unsigned short*)(wsf + 2048 + 65536);
    float* partials = wsf + 2048 + 131072;

    const int N = in_sizes[0] / ND;  // 131072
    const int nrowtiles = N >> 7;    // 1024

    prep_kernel<<<NK, 64, 0, stream>>>(Cg, csq, Chi, Clo);
    kmeans_mfma<<<nrowtiles * 4, 256, 0, stream>>>(E, Chi, Clo, csq, partials, e2s);
    combine_kernel<<<N / 256, 256, 0, stream>>>(partials, csq, E, Cg, out, sum2);
    final_kernel<<<1, 256, 0, stream>>>(e2s, sum2, out);
}

// Round 3
// 191.973 us; speedup vs baseline: 2.1163x; 1.0547x over previous
//
#include <hip/hip_runtime.h>

#define ND 256       // embedding dim
#define NK 512       // centroids
#define BK 64        // k-chunk per LDS stage
#define NT (ND / BK) // 4 stages
#define LM2 0.0625f  // lambda^2
#define DELTA 0.25f  // approx top-2 gap below this -> exact fp32 rescore (~19 sigma)

typedef _Float16 f16x8 __attribute__((ext_vector_type(8)));
typedef float f32x4 __attribute__((ext_vector_type(4)));
typedef unsigned short u16x8 __attribute__((ext_vector_type(8)));
typedef unsigned short u16x4 __attribute__((ext_vector_type(4)));

// 128x64 fp16 tile, row stride 64 elems (128 B). XOR swizzle spreads the
// 8 16B-slots of a row across banks by row&7: frag reads (16 rows) -> 2-way
// max (free), staging writes (32 rows) -> 4-way.
#define SW(r, c) ((((r) << 6) + (c)) ^ (((r)&7) << 3))

// ---------------- prep: csq[k] and fp16 centroids ----------------
__global__ __launch_bounds__(64) void prep_kernel(const float* __restrict__ Cg,
                                                  float* __restrict__ csq,
                                                  unsigned short* __restrict__ Cf) {
    const int k = blockIdx.x, lane = threadIdx.x;
    float4 v = *(const float4*)(Cg + (size_t)k * ND + lane * 4);
    float s = v.x * v.x + v.y * v.y + v.z * v.z + v.w * v.w;
#pragma unroll
    for (int m = 1; m <= 32; m <<= 1) s += __shfl_xor(s, m, 64);
    if (lane == 0) csq[k] = s;
    u16x4 h;
    h[0] = __builtin_bit_cast(unsigned short, (_Float16)v.x);
    h[1] = __builtin_bit_cast(unsigned short, (_Float16)v.y);
    h[2] = __builtin_bit_cast(unsigned short, (_Float16)v.z);
    h[3] = __builtin_bit_cast(unsigned short, (_Float16)v.w);
    *(u16x4*)(Cf + (size_t)k * ND + lane * 4) = h;
}

// ---------------- main: fp16 MFMA GEMM + per-row top-2 ----------------
// grid 4096 = 1024 rowtiles x 4 colblks, XCD-chunked so a rowtile's 4 colblks
// share one XCD's L2 (E fetched from HBM ~once). block: 4 waves, wave 64x64.
__global__ __launch_bounds__(256, 2) void kmeans_mfma(
    const float* __restrict__ E, const unsigned short* __restrict__ Cf,
    const float* __restrict__ csq, float* __restrict__ partials,
    float* __restrict__ e2s) {
    __shared__ unsigned short Ah[128 * 64];  // 16 KB
    __shared__ unsigned short Bh[128 * 64];  // 16 KB
    __shared__ float mbuf[128][2][4];
    __shared__ float wsum[4];

    const int tid = threadIdx.x;
    const int l = ((blockIdx.x & 7) << 9) + (blockIdx.x >> 3);  // chunked XCD swizzle
    const int rowtile = l >> 2, colblk = l & 3;
    const int rowbase = rowtile << 7, colbase = colblk << 7;

    const int lane = tid & 63, wid = tid >> 6;
    const int wr = wid >> 1, wc = wid & 1;
    const int l15 = lane & 15, l4 = lane >> 4;

    const int srow = tid >> 1, skb = (tid & 1) << 5;  // staging: row, k-base (32 wide)
    const float* Arow = E + (size_t)(rowbase + srow) * ND + skb;
    const unsigned short* Brow = Cf + (size_t)(colbase + srow) * ND + skb;

    f32x4 acc[4][4] = {};
    float e2 = 0.f;

    // prologue: t=0 global loads (A: 32 floats, B: 32 halves per thread)
    float4 ar[8];
    u16x8 br[4];
#pragma unroll
    for (int j = 0; j < 8; ++j) ar[j] = *(const float4*)(Arow + j * 4);
#pragma unroll
    for (int j = 0; j < 4; ++j) br[j] = *(const u16x8*)(Brow + j * 8);

    for (int t = 0; t < NT; ++t) {
        // ---- convert A to fp16 (and e2 on colblk 0); stash B ----
        u16x8 hA[4];
        u16x8 bs[4];
#pragma unroll
        for (int q = 0; q < 4; ++q) {
            float4 v0 = ar[q * 2], v1 = ar[q * 2 + 1];
            if (colblk == 0)
                e2 += v0.x * v0.x + v0.y * v0.y + v0.z * v0.z + v0.w * v0.w +
                      v1.x * v1.x + v1.y * v1.y + v1.z * v1.z + v1.w * v1.w;
            u16x8 h;
            h[0] = __builtin_bit_cast(unsigned short, (_Float16)v0.x);
            h[1] = __builtin_bit_cast(unsigned short, (_Float16)v0.y);
            h[2] = __builtin_bit_cast(unsigned short, (_Float16)v0.z);
            h[3] = __builtin_bit_cast(unsigned short, (_Float16)v0.w);
            h[4] = __builtin_bit_cast(unsigned short, (_Float16)v1.x);
            h[5] = __builtin_bit_cast(unsigned short, (_Float16)v1.y);
            h[6] = __builtin_bit_cast(unsigned short, (_Float16)v1.z);
            h[7] = __builtin_bit_cast(unsigned short, (_Float16)v1.w);
            hA[q] = h;
            bs[q] = br[q];
        }
        // ---- prefetch t+1 (in flight across LDS writes + MFMA phase) ----
        if (t < NT - 1) {
            const int d0 = (t + 1) * BK;
#pragma unroll
            for (int j = 0; j < 8; ++j) ar[j] = *(const float4*)(Arow + d0 + j * 4);
#pragma unroll
            for (int j = 0; j < 4; ++j) br[j] = *(const u16x8*)(Brow + d0 + j * 8);
        }
        // ---- LDS stage (swizzled) ----
#pragma unroll
        for (int q = 0; q < 4; ++q) {
            *(u16x8*)&Ah[SW(srow, skb + q * 8)] = hA[q];
            *(u16x8*)&Bh[SW(srow, skb + q * 8)] = bs[q];
        }
        __syncthreads();
        // ---- 2 k-steps x 16 MFMA ----
#pragma unroll
        for (int ks = 0; ks < BK; ks += 32) {
            f16x8 fa[4], fb[4];
#pragma unroll
            for (int m = 0; m < 4; ++m)
                fa[m] = __builtin_bit_cast(f16x8, *(const u16x8*)&Ah[SW(wr * 64 + m * 16 + l15, ks + l4 * 8)]);
#pragma unroll
            for (int n = 0; n < 4; ++n)
                fb[n] = __builtin_bit_cast(f16x8, *(const u16x8*)&Bh[SW(wc * 64 + n * 16 + l15, ks + l4 * 8)]);
#pragma unroll
            for (int m = 0; m < 4; ++m)
#pragma unroll
                for (int n = 0; n < 4; ++n)
                    acc[m][n] = __builtin_amdgcn_mfma_f32_16x16x32_f16(fa[m], fb[n], acc[m][n], 0, 0, 0);
        }
        __syncthreads();
    }

    // ---- epilogue: per-row top-2 of s = csq[k] - 2*cross over 128 cols ----
#pragma unroll
    for (int m = 0; m < 4; ++m) {
#pragma unroll
        for (int j = 0; j < 4; ++j) {
            float v1 = -3.4e38f, v2 = -3.4e38f;
            int i1 = 0, i2 = 0;
#pragma unroll
            for (int n = 0; n < 4; ++n) {
                const int col = colbase + wc * 64 + n * 16 + l15;
                const float s = csq[col] - 2.0f * acc[m][n][j];
                if (s > v1) { v2 = v1; i2 = i1; v1 = s; i1 = col; }
                else if (s > v2) { v2 = s; i2 = col; }
            }
#pragma unroll
            for (int mk = 1; mk <= 8; mk <<= 1) {
                float ov1 = __shfl_xor(v1, mk, 64); int oi1 = __shfl_xor(i1, mk, 64);
                float ov2 = __shfl_xor(v2, mk, 64); int oi2 = __shfl_xor(i2, mk, 64);
                bool af = (v1 > ov1) || (v1 == ov1 && i1 < oi1);
                float f1 = af ? v1 : ov1; int g1 = af ? i1 : oi1;
                float c1 = af ? v2 : ov2; int d1 = af ? i2 : oi2;
                float c2 = af ? ov1 : v1; int d2 = af ? oi1 : i1;
                bool cf = (c1 > c2) || (c1 == c2 && d1 < d2);
                v1 = f1; i1 = g1; v2 = cf ? c1 : c2; i2 = cf ? d1 : d2;
            }
            if (l15 == 0) {
                const int rl = wr * 64 + m * 16 + l4 * 4 + j;
                mbuf[rl][wc][0] = v1; mbuf[rl][wc][1] = (float)i1;
                mbuf[rl][wc][2] = v2; mbuf[rl][wc][3] = (float)i2;
            }
        }
    }
    if (colblk == 0) {
        float tot = e2;
#pragma unroll
        for (int mk = 1; mk <= 32; mk <<= 1) tot += __shfl_xor(tot, mk, 64);
        if (lane == 0) wsum[wid] = tot;
    }
    __syncthreads();
    if (tid < 128) {
        float a1 = mbuf[tid][0][0]; int ai1 = (int)mbuf[tid][0][1];
        float a2 = mbuf[tid][0][2]; int ai2 = (int)mbuf[tid][0][3];
        float b1 = mbuf[tid][1][0]; int bi1 = (int)mbuf[tid][1][1];
        float b2 = mbuf[tid][1][2]; int bi2 = (int)mbuf[tid][1][3];
        bool af = (a1 > b1) || (a1 == b1 && ai1 < bi1);
        float f1 = af ? a1 : b1; int g1 = af ? ai1 : bi1;
        float c1 = af ? a2 : b2; int d1 = af ? ai2 : bi2;
        float c2 = af ? b1 : a1; int d2 = af ? bi1 : ai1;
        bool cf = (c1 > c2) || (c1 == c2 && d1 < d2);
        float f2 = cf ? c1 : c2; int g2 = cf ? d1 : d2;
        float4 o = {f1, (float)g1, f2, (float)g2};
        *(float4*)(partials + ((size_t)(rowbase + tid) * 4 + colblk) * 4) = o;
    }
    if (colblk == 0 && tid == 0) e2s[rowtile] = wsum[0] + wsum[1] + wsum[2] + wsum[3];
}

// ---------------- combine: merge 4 col-block top-2s, rescore near-ties ----------------
__global__ __launch_bounds__(256) void combine_kernel(
    const float* __restrict__ partials, const float* __restrict__ csq,
    const float* __restrict__ E, const float* __restrict__ Cg,
    float* __restrict__ out, float* __restrict__ sum2) {
    const int n = blockIdx.x * 256 + threadIdx.x;
    const float4* p = (const float4*)(partials + (size_t)n * 16);
    float4 a = p[0];
    float v1 = a.x; int i1 = (int)a.y; float v2 = a.z; int i2 = (int)a.w;
#pragma unroll
    for (int cb = 1; cb < 4; ++cb) {
        float4 b = p[cb];
        float b1 = b.x; int j1 = (int)b.y; float b2 = b.z; int j2 = (int)b.w;
        bool af = (v1 > b1) || (v1 == b1 && i1 < j1);
        float f1 = af ? v1 : b1; int g1 = af ? i1 : j1;
        float c1 = af ? v2 : b2; int d1 = af ? i2 : j2;
        float c2 = af ? b1 : v1; int d2 = af ? j1 : i1;
        bool cf = (c1 > c2) || (c1 == c2 && d1 < d2);
        v1 = f1; i1 = g1; v2 = cf ? c1 : c2; i2 = cf ? d1 : d2;
    }
    if (v1 - v2 <= DELTA) {  // near-tie: exact fp32 rescore of both candidates
        const float* e = E + (size_t)n * ND;
        const float* c1p = Cg + (size_t)i1 * ND;
        const float* c2p = Cg + (size_t)i2 * ND;
        float d1 = 0.f, d2 = 0.f;
        for (int d = 0; d < ND; d += 4) {
            float4 ev = *(const float4*)(e + d);
            float4 cv1 = *(const float4*)(c1p + d);
            float4 cv2 = *(const float4*)(c2p + d);
            d1 += ev.x * cv1.x + ev.y * cv1.y + ev.z * cv1.z + ev.w * cv1.w;
            d2 += ev.x * cv2.x + ev.y * cv2.y + ev.z * cv2.z + ev.w * cv2.w;
        }
        float s1 = csq[i1] - 2.f * d1;
        float s2 = csq[i2] - 2.f * d2;
        if (s2 > s1 || (s2 == s1 && i2 < i1)) { v1 = s2; i1 = i2; } else { v1 = s1; }
    }
    out[1 + n] = (float)i1;
    float s = v1;
#pragma unroll
    for (int mk = 1; mk <= 32; mk <<= 1) s += __shfl_xor(s, mk, 64);
    __shared__ float w[4];
    const int lane = threadIdx.x & 63, wd = threadIdx.x >> 6;
    if (lane == 0) w[wd] = s;
    __syncthreads();
    if (threadIdx.x == 0) sum2[blockIdx.x] = w[0] + w[1] + w[2] + w[3];
}

// ---------------- final: loss = lambda^2 * (sum e^2 + sum row maxima) ----------------
__global__ __launch_bounds__(256) void final_kernel(const float* __restrict__ e2s,
                                                    const float* __restrict__ sum2,
                                                    float* __restrict__ out) {
    float s = 0.f;
    for (int i = threadIdx.x; i < 1024; i += 256) s += e2s[i];
    for (int i = threadIdx.x; i < 512; i += 256) s += sum2[i];
#pragma unroll
    for (int mk = 1; mk <= 32; mk <<= 1) s += __shfl_xor(s, mk, 64);
    __shared__ float w[4];
    const int lane = threadIdx.x & 63, wd = threadIdx.x >> 6;
    if (lane == 0) w[wd] = s;
    __syncthreads();
    if (threadIdx.x == 0) out[0] = LM2 * (w[0] + w[1] + w[2] + w[3]);
}

extern "C" void kernel_launch(void* const* d_in, const int* in_sizes, int n_in,
                              void* d_out, int out_size, void* d_ws, size_t ws_size,
                              hipStream_t stream) {
    (void)n_in; (void)out_size; (void)ws_size;
    const float* E = (const float*)d_in[0];
    const float* Cg = (const float*)d_in[1];
    float* out = (float*)d_out;

    // ws (floats): csq[512] | e2s[1024] | sum2[512] | Cf16 (256KB) | partials (8MB)
    float* wsf = (float*)d_ws;
    float* csq = wsf;
    float* e2s = wsf + 512;
    float* sum2 = wsf + 1536;
    unsigned short* Cf = (unsigned short*)(wsf + 2048);
    float* partials = wsf + 2048 + 65536;

    const int N = in_sizes[0] / ND;  // 131072
    const int nrowtiles = N >> 7;    // 1024

    prep_kernel<<<NK, 64, 0, stream>>>(Cg, csq, Cf);
    kmeans_mfma<<<nrowtiles * 4, 256, 0, stream>>>(E, Cf, csq, partials, e2s);
    combine_kernel<<<N / 256, 256, 0, stream>>>(partials, csq, E, Cg, out, sum2);
    final_kernel<<<1, 256, 0, stream>>>(e2s, sum2, out);
}

// Round 4
// 141.749 us; speedup vs baseline: 2.8661x; 1.3543x over previous
//
#include <hip/hip_runtime.h>

#define ND 256       // embedding dim
#define NK 512       // centroids
#define LM2 0.0625f  // lambda^2
#define DELTA 0.25f  // approx top-2 gap below this -> exact fp32 rescore

typedef _Float16 f16x8 __attribute__((ext_vector_type(8)));
typedef float f32x4 __attribute__((ext_vector_type(4)));
typedef unsigned short u16x8 __attribute__((ext_vector_type(8)));
typedef unsigned short u16x4 __attribute__((ext_vector_type(4)));

// ---------------- prep: csq[k] and fp16 centroids in MFMA-B-fragment order ----
// Cf layout: [colblk 4][(ks*4+l4) 32][col 128][8 halves]  (granule = 16B = one
// lane's B-frag slice). Main kernel then stages a colblk's panel with a LINEAR
// 64KB copy and reads frags conflict-free with one address register.
__global__ __launch_bounds__(64) void prep_kernel(const float* __restrict__ Cg,
                                                  float* __restrict__ csq,
                                                  unsigned short* __restrict__ Cf) {
    const int k = blockIdx.x, lane = threadIdx.x;
    float4 v = *(const float4*)(Cg + (size_t)k * ND + lane * 4);
    float s = v.x * v.x + v.y * v.y + v.z * v.z + v.w * v.w;
#pragma unroll
    for (int m = 1; m <= 32; m <<= 1) s += __shfl_xor(s, m, 64);
    if (lane == 0) csq[k] = s;
    u16x4 h;
    h[0] = __builtin_bit_cast(unsigned short, (_Float16)v.x);
    h[1] = __builtin_bit_cast(unsigned short, (_Float16)v.y);
    h[2] = __builtin_bit_cast(unsigned short, (_Float16)v.z);
    h[3] = __builtin_bit_cast(unsigned short, (_Float16)v.w);
    const int colblk = k >> 7, col = k & 127;
    const size_t idx = (size_t)colblk * 32768 + (((size_t)(lane >> 1) * 128 + col) << 3) + ((lane & 1) << 2);
    *(u16x4*)(Cf + idx) = h;
}

// ---------------- main: B-once-in-LDS, A global->reg->fp16->MFMA ----------------
// grid 4096 = 1024 rowtiles x 4 colblks (XCD-chunked). Block: 4 waves, 128 rows.
// Wave: 32 rows x 128 cols, barrier-free K-loop (ONE __syncthreads total).
__global__ __launch_bounds__(256, 2) void kmeans_mfma(
    const float* __restrict__ E, const unsigned short* __restrict__ Cf,
    const float* __restrict__ csq, float* __restrict__ partials,
    float* __restrict__ e2s) {
    __shared__ unsigned short Blds[32768];  // 64 KB

    const int tid = threadIdx.x;
    const int l = ((blockIdx.x & 7) << 9) + (blockIdx.x >> 3);  // chunked XCD swizzle
    const int rowtile = l >> 2, colblk = l & 3;
    const int rowbase = rowtile << 7, colbase = colblk << 7;

    const int lane = tid & 63, wid = tid >> 6;
    const int l15 = lane & 15, l4 = lane >> 4;

    // ---- stage B panel (linear 64 KB copy), one barrier ----
    const unsigned short* CfB = Cf + (size_t)colblk * 32768;
#pragma unroll 4
    for (int i = 0; i < 16; ++i) {
        const int g = tid + i * 256;
        *(u16x8*)&Blds[g << 3] = *(const u16x8*)(CfB + ((size_t)g << 3));
    }
    __syncthreads();

    // ---- barrier-free K-loop ----
    const int wrow = rowbase + wid * 32;
    const float* a0 = E + (size_t)(wrow + l15) * ND + l4 * 8;        // m=0 rows
    const float* a1 = E + (size_t)(wrow + 16 + l15) * ND + l4 * 8;   // m=1 rows

    f32x4 acc[2][8] = {};
    float e2 = 0.f;

    float4 aN[2][2];
    aN[0][0] = *(const float4*)(a0 + 0); aN[0][1] = *(const float4*)(a0 + 4);
    aN[1][0] = *(const float4*)(a1 + 0); aN[1][1] = *(const float4*)(a1 + 4);

#pragma unroll
    for (int ks = 0; ks < 8; ++ks) {
        // B frags for this ks (one b128 each; offsets fold into immediates)
        u16x8 bf[8];
#pragma unroll
        for (int n = 0; n < 8; ++n)
            bf[n] = *(const u16x8*)&Blds[((((ks << 2) + l4) << 7) + n * 16 + l15) << 3];
        // convert current A chunk
        f16x8 af[2];
#pragma unroll
        for (int m = 0; m < 2; ++m) {
            float4 v0 = aN[m][0], v1 = aN[m][1];
            if (colblk == 0)
                e2 += v0.x * v0.x + v0.y * v0.y + v0.z * v0.z + v0.w * v0.w +
                      v1.x * v1.x + v1.y * v1.y + v1.z * v1.z + v1.w * v1.w;
            u16x8 h;
            h[0] = __builtin_bit_cast(unsigned short, (_Float16)v0.x);
            h[1] = __builtin_bit_cast(unsigned short, (_Float16)v0.y);
            h[2] = __builtin_bit_cast(unsigned short, (_Float16)v0.z);
            h[3] = __builtin_bit_cast(unsigned short, (_Float16)v0.w);
            h[4] = __builtin_bit_cast(unsigned short, (_Float16)v1.x);
            h[5] = __builtin_bit_cast(unsigned short, (_Float16)v1.y);
            h[6] = __builtin_bit_cast(unsigned short, (_Float16)v1.z);
            h[7] = __builtin_bit_cast(unsigned short, (_Float16)v1.w);
            af[m] = __builtin_bit_cast(f16x8, h);
        }
        // prefetch next A chunk (no barrier in the way -> latency hides under MFMA)
        if (ks < 7) {
            const int d = (ks + 1) * 32;
            aN[0][0] = *(const float4*)(a0 + d); aN[0][1] = *(const float4*)(a0 + d + 4);
            aN[1][0] = *(const float4*)(a1 + d); aN[1][1] = *(const float4*)(a1 + d + 4);
        }
#pragma unroll
        for (int m = 0; m < 2; ++m)
#pragma unroll
            for (int n = 0; n < 8; ++n)
                acc[m][n] = __builtin_amdgcn_mfma_f32_16x16x32_f16(af[m], bf[n], acc[m][n], 0, 0, 0);
    }

    // ---- epilogue: per-row top-2 over this block's 128 cols ----
    float cs[8];
#pragma unroll
    for (int n = 0; n < 8; ++n) cs[n] = csq[colbase + n * 16 + l15];

#pragma unroll
    for (int m = 0; m < 2; ++m) {
#pragma unroll
        for (int j = 0; j < 4; ++j) {
            float v1 = -3.4e38f, v2 = -3.4e38f;
            int i1 = 0, i2 = 0;
#pragma unroll
            for (int n = 0; n < 8; ++n) {
                const int col = colbase + n * 16 + l15;
                const float s = cs[n] - 2.0f * acc[m][n][j];
                if (s > v1) { v2 = v1; i2 = i1; v1 = s; i1 = col; }
                else if (s > v2) { v2 = s; i2 = col; }
            }
#pragma unroll
            for (int mk = 1; mk <= 8; mk <<= 1) {
                float ov1 = __shfl_xor(v1, mk, 64); int oi1 = __shfl_xor(i1, mk, 64);
                float ov2 = __shfl_xor(v2, mk, 64); int oi2 = __shfl_xor(i2, mk, 64);
                bool af_ = (v1 > ov1) || (v1 == ov1 && i1 < oi1);
                float f1 = af_ ? v1 : ov1; int g1 = af_ ? i1 : oi1;
                float c1 = af_ ? v2 : ov2; int d1 = af_ ? i2 : oi2;
                float c2 = af_ ? ov1 : v1; int d2 = af_ ? oi1 : i1;
                bool cf = (c1 > c2) || (c1 == c2 && d1 < d2);
                v1 = f1; i1 = g1; v2 = cf ? c1 : c2; i2 = cf ? d1 : d2;
            }
            if (l15 == 0) {
                const int row = wrow + m * 16 + l4 * 4 + j;
                float4 o = {v1, (float)i1, v2, (float)i2};
                *(float4*)(partials + (((size_t)row * 4 + colblk) << 2)) = o;
            }
        }
    }
    if (colblk == 0) {
#pragma unroll
        for (int mk = 1; mk <= 32; mk <<= 1) e2 += __shfl_xor(e2, mk, 64);
        if (lane == 0) e2s[rowtile * 4 + wid] = e2;
    }
}

// ---------------- combine: merge 4 col-block top-2s, rescore near-ties ----------------
__global__ __launch_bounds__(256) void combine_kernel(
    const float* __restrict__ partials, const float* __restrict__ csq,
    const float* __restrict__ E, const float* __restrict__ Cg,
    float* __restrict__ out, float* __restrict__ sum2) {
    const int n = blockIdx.x * 256 + threadIdx.x;
    const float4* p = (const float4*)(partials + (size_t)n * 16);
    float4 a = p[0];
    float v1 = a.x; int i1 = (int)a.y; float v2 = a.z; int i2 = (int)a.w;
#pragma unroll
    for (int cb = 1; cb < 4; ++cb) {
        float4 b = p[cb];
        float b1 = b.x; int j1 = (int)b.y; float b2 = b.z; int j2 = (int)b.w;
        bool af = (v1 > b1) || (v1 == b1 && i1 < j1);
        float f1 = af ? v1 : b1; int g1 = af ? i1 : j1;
        float c1 = af ? v2 : b2; int d1 = af ? i2 : j2;
        float c2 = af ? b1 : v1; int d2 = af ? j1 : i1;
        bool cf = (c1 > c2) || (c1 == c2 && d1 < d2);
        v1 = f1; i1 = g1; v2 = cf ? c1 : c2; i2 = cf ? d1 : d2;
    }
    if (v1 - v2 <= DELTA) {  // near-tie: exact fp32 rescore of both candidates
        const float* e = E + (size_t)n * ND;
        const float* c1p = Cg + (size_t)i1 * ND;
        const float* c2p = Cg + (size_t)i2 * ND;
        float d1 = 0.f, d2 = 0.f;
        for (int d = 0; d < ND; d += 4) {
            float4 ev = *(const float4*)(e + d);
            float4 cv1 = *(const float4*)(c1p + d);
            float4 cv2 = *(const float4*)(c2p + d);
            d1 += ev.x * cv1.x + ev.y * cv1.y + ev.z * cv1.z + ev.w * cv1.w;
            d2 += ev.x * cv2.x + ev.y * cv2.y + ev.z * cv2.z + ev.w * cv2.w;
        }
        float s1 = csq[i1] - 2.f * d1;
        float s2 = csq[i2] - 2.f * d2;
        if (s2 > s1 || (s2 == s1 && i2 < i1)) { v1 = s2; i1 = i2; } else { v1 = s1; }
    }
    out[1 + n] = (float)i1;
    float s = v1;
#pragma unroll
    for (int mk = 1; mk <= 32; mk <<= 1) s += __shfl_xor(s, mk, 64);
    __shared__ float w[4];
    const int lane = threadIdx.x & 63, wd = threadIdx.x >> 6;
    if (lane == 0) w[wd] = s;
    __syncthreads();
    if (threadIdx.x == 0) sum2[blockIdx.x] = w[0] + w[1] + w[2] + w[3];
}

// ---------------- final: loss = lambda^2 * (sum e^2 + sum row maxima) ----------------
__global__ __launch_bounds__(256) void final_kernel(const float* __restrict__ e2s,
                                                    const float* __restrict__ sum2,
                                                    float* __restrict__ out) {
    float s = 0.f;
    for (int i = threadIdx.x; i < 4096; i += 256) s += e2s[i];
    for (int i = threadIdx.x; i < 512; i += 256) s += sum2[i];
#pragma unroll
    for (int mk = 1; mk <= 32; mk <<= 1) s += __shfl_xor(s, mk, 64);
    __shared__ float w[4];
    const int lane = threadIdx.x & 63, wd = threadIdx.x >> 6;
    if (lane == 0) w[wd] = s;
    __syncthreads();
    if (threadIdx.x == 0) out[0] = LM2 * (w[0] + w[1] + w[2] + w[3]);
}

extern "C" void kernel_launch(void* const* d_in, const int* in_sizes, int n_in,
                              void* d_out, int out_size, void* d_ws, size_t ws_size,
                              hipStream_t stream) {
    (void)n_in; (void)out_size; (void)ws_size;
    const float* E = (const float*)d_in[0];
    const float* Cg = (const float*)d_in[1];
    float* out = (float*)d_out;

    // ws (floats): csq[512] | e2s[4096] | sum2[512] | Cf16 (256KB) | partials (8MB)
    float* wsf = (float*)d_ws;
    float* csq = wsf;
    float* e2s = wsf + 512;
    float* sum2 = wsf + 4608;
    unsigned short* Cf = (unsigned short*)(wsf + 5120);
    float* partials = wsf + 5120 + 65536;

    const int N = in_sizes[0] / ND;  // 131072
    const int nrowtiles = N >> 7;    // 1024

    prep_kernel<<<NK, 64, 0, stream>>>(Cg, csq, Cf);
    kmeans_mfma<<<nrowtiles * 4, 256, 0, stream>>>(E, Cf, csq, partials, e2s);
    combine_kernel<<<N / 256, 256, 0, stream>>>(partials, csq, E, Cg, out, sum2);
    final_kernel<<<1, 256, 0, stream>>>(e2s, sum2, out);
}